// Round 1
// baseline (61.665 us; speedup 1.0000x reference)
//
#include <hip/hip_runtime.h>
#include <hip/hip_bf16.h>

// ScaledPredictionLayer: per-row Mahalanobis distance with symmetric 6x6
// inverse covariance reconstructed from 21 upper-triangular elements.
//
// Memory-bound: 136 B read + 4 B write per row, B = 2M rows -> ~294 MB.
// Each thread processes TWO rows so every global access is a 16B-aligned
// float4 (scaled pair = 48 B, pred pair = 224 B, out pair = float2).

__global__ __launch_bounds__(256) void spl_kernel(
    const float* __restrict__ scaled,   // (B,6)
    const float* __restrict__ pred,     // (B,28)
    const float* __restrict__ pmean,    // (6,)
    const float* __restrict__ pscale,   // (6,)
    const float* __restrict__ tmean,    // (1,)
    const float* __restrict__ tscale,   // (1,)
    float* __restrict__ out,            // (B,1)
    int npairs)                         // B/2
{
    int t = blockIdx.x * blockDim.x + threadIdx.x;
    if (t >= npairs) return;

    // Broadcast constants (L1-resident after first wave).
    float m[6], s[6];
#pragma unroll
    for (int i = 0; i < 6; ++i) { m[i] = pmean[i]; s[i] = pscale[i]; }
    const float tm     = tmean[0];
    const float inv_ts = 1.0f / tscale[0];

    const size_t row0 = (size_t)t * 2;

    // scaled rows [row0, row0+1]: 12 floats, 48 B, 16-aligned.
    float4 sc[3];
    const float4* sp = reinterpret_cast<const float4*>(scaled + row0 * 6);
#pragma unroll
    for (int i = 0; i < 3; ++i) sc[i] = sp[i];

    // pred rows: 56 floats, 224 B, 16-aligned.
    float4 pp[14];
    const float4* ppv = reinterpret_cast<const float4*>(pred + row0 * 28);
#pragma unroll
    for (int i = 0; i < 14; ++i) pp[i] = ppv[i];

    const float* scf = reinterpret_cast<const float*>(sc);
    const float* pf  = reinterpret_cast<const float*>(pp);

    float2 res;
#pragma unroll
    for (int r = 0; r < 2; ++r) {
        const float* s6  = scf + r * 6;
        const float* p28 = pf  + r * 28;

        float dp[6];
#pragma unroll
        for (int i = 0; i < 6; ++i)
            dp[i] = fmaf(s6[i], s[i], m[i]) - p28[1 + i];

        // mahalanobis = sum over upper triangle: w * c_k * dp_i * dp_j,
        // w = 1 on diagonal, 2 off-diagonal (symmetric matrix).
        float mah = 0.0f;
        int k = 7;
#pragma unroll
        for (int i = 0; i < 6; ++i) {
#pragma unroll
            for (int j = i; j < 6; ++j) {
                const float w = (i == j) ? 1.0f : 2.0f;
                mah = fmaf(w * p28[k], dp[i] * dp[j], mah);
                ++k;
            }
        }

        const float v = p28[0] + 0.5f * mah;
        (&res.x)[r] = (v - tm) * inv_ts;
    }

    reinterpret_cast<float2*>(out)[t] = res;
}

extern "C" void kernel_launch(void* const* d_in, const int* in_sizes, int n_in,
                              void* d_out, int out_size, void* d_ws, size_t ws_size,
                              hipStream_t stream) {
    const float* scaled = (const float*)d_in[0];
    const float* pred   = (const float*)d_in[1];
    const float* pmean  = (const float*)d_in[2];
    const float* pscale = (const float*)d_in[3];
    const float* tmean  = (const float*)d_in[4];
    const float* tscale = (const float*)d_in[5];
    float* out = (float*)d_out;

    const int B = in_sizes[0] / 6;      // 2097152
    const int npairs = B / 2;           // B is even
    const int block = 256;
    const int grid = (npairs + block - 1) / block;

    spl_kernel<<<grid, block, 0, stream>>>(scaled, pred, pmean, pscale,
                                           tmean, tscale, out, npairs);
}

// Round 2
// 47.203 us; speedup vs baseline: 1.3064x; 1.3064x over previous
//
#include <hip/hip_runtime.h>
#include <hip/hip_bf16.h>

// ScaledPredictionLayer: per-row Mahalanobis with symmetric 6x6 inverse cov
// from 21 upper-tri elements. Memory-bound: 136 B read + 4 B write per row.
//
// R2: block-cooperative coalesced staging through LDS. Direct per-row float4
// loads had 224 B inter-lane stride (scattered lines, L1 thrash, ~4.8 TB/s).
// Coalesced lane->consecutive-float4 staging is the 6.3 TB/s pattern.

#define ROWS_PER_BLOCK 256

__global__ __launch_bounds__(256) void spl_kernel(
    const float* __restrict__ scaled,   // (B,6)
    const float* __restrict__ pred,     // (B,28)
    const float* __restrict__ pmean,    // (6,)
    const float* __restrict__ pscale,   // (6,)
    const float* __restrict__ tmean,    // (1,)
    const float* __restrict__ tscale,   // (1,)
    float* __restrict__ out,            // (B,1)
    int nrows)
{
    __shared__ float lds_pred[ROWS_PER_BLOCK * 28];   // 28 KiB
    __shared__ float lds_sc  [ROWS_PER_BLOCK * 6];    // 6 KiB

    const int tid = threadIdx.x;
    const size_t row_base = (size_t)blockIdx.x * ROWS_PER_BLOCK;

    // ---- coalesced staging: lane i -> float4 index i + 256*k ----
    // pred chunk: 256 rows * 28 floats = 1792 float4 (rows are 7 float4 each,
    // so no float4 straddles a row boundary).
    {
        const float4* gp = reinterpret_cast<const float4*>(pred + row_base * 28);
        float4* lp = reinterpret_cast<float4*>(lds_pred);
#pragma unroll
        for (int k = 0; k < 7; ++k)
            lp[tid + 256 * k] = gp[tid + 256 * k];
    }
    // scaled chunk: 256 rows * 6 floats = 384 float4.
    {
        const float4* gs = reinterpret_cast<const float4*>(scaled + row_base * 6);
        float4* ls = reinterpret_cast<float4*>(lds_sc);
        ls[tid] = gs[tid];
        if (tid < 128) ls[256 + tid] = gs[256 + tid];
    }

    // Broadcast constants (same line for all threads -> cached/broadcast).
    float m[6], s[6];
#pragma unroll
    for (int i = 0; i < 6; ++i) { m[i] = pmean[i]; s[i] = pscale[i]; }
    const float tm     = tmean[0];
    const float inv_ts = 1.0f / tscale[0];

    __syncthreads();

    // ---- compute: thread tid owns row (row_base + tid) ----
    float p28[28];
#pragma unroll
    for (int j = 0; j < 7; ++j)
        *reinterpret_cast<float4*>(&p28[4 * j]) =
            *reinterpret_cast<const float4*>(&lds_pred[tid * 28 + 4 * j]);

    float s6[6];
#pragma unroll
    for (int j = 0; j < 3; ++j)
        *reinterpret_cast<float2*>(&s6[2 * j]) =
            *reinterpret_cast<const float2*>(&lds_sc[tid * 6 + 2 * j]);

    float dp[6];
#pragma unroll
    for (int i = 0; i < 6; ++i)
        dp[i] = fmaf(s6[i], s[i], m[i]) - p28[1 + i];

    // mahalanobis = sum over upper triangle: w * c_k * dp_i * dp_j,
    // w = 1 diagonal, 2 off-diagonal.
    float mah = 0.0f;
    int k = 7;
#pragma unroll
    for (int i = 0; i < 6; ++i) {
#pragma unroll
        for (int j = i; j < 6; ++j) {
            const float w = (i == j) ? 1.0f : 2.0f;
            mah = fmaf(w * p28[k], dp[i] * dp[j], mah);
            ++k;
        }
    }

    const float v = p28[0] + 0.5f * mah;
    const size_t row = row_base + tid;
    if (row < (size_t)nrows)
        out[row] = (v - tm) * inv_ts;
}

extern "C" void kernel_launch(void* const* d_in, const int* in_sizes, int n_in,
                              void* d_out, int out_size, void* d_ws, size_t ws_size,
                              hipStream_t stream) {
    const float* scaled = (const float*)d_in[0];
    const float* pred   = (const float*)d_in[1];
    const float* pmean  = (const float*)d_in[2];
    const float* pscale = (const float*)d_in[3];
    const float* tmean  = (const float*)d_in[4];
    const float* tscale = (const float*)d_in[5];
    float* out = (float*)d_out;

    const int B = in_sizes[0] / 6;                    // 2,097,152 (multiple of 256)
    const int grid = B / ROWS_PER_BLOCK;
    spl_kernel<<<grid, ROWS_PER_BLOCK, 0, stream>>>(scaled, pred, pmean, pscale,
                                                    tmean, tscale, out, B);
}